// Round 2
// baseline (347.211 us; speedup 1.0000x reference)
//
#include <hip/hip_runtime.h>
#include <math.h>

#define B_ 8
#define N_ 16384
#define G_ 128      // NUM_GROUPS
#define GS_ 32      // GROUP_SIZE
#define UK_ 128     // UPSCALE_K
#define FPS_T 1024
#define FPS_W 16    // waves per FPS block
#define PPT 16      // points per thread (N_ / FPS_T), all resident in VGPRs
#define BQ_T 512
#define BQ_W 8      // waves per group block

typedef float v2f __attribute__((ext_vector_type(2)));

// Packed fp32 ops (gfx90a+ VOP3P). Same IEEE rounding as scalar v_add/v_mul.
// Subtraction is done as x + (-c): negation is exact, so rounding matches x - c.
#define PK_ADD(d, a, b) asm("v_pk_add_f32 %0, %1, %2" : "=v"(d) : "v"(a), "v"(b))
#define PK_MUL(d, a, b) asm("v_pk_mul_f32 %0, %1, %2" : "=v"(d) : "v"(a), "v"(b))

// 64-bit max-combine with a DPP-shifted copy of vv. Same ctrl/row_mask ladder as
// the proven u32 wave_umax (old=0 for masked/bound lanes == identity for max).
#define DPP64_MAXSTEP(vv, ctrl, rmask)                                          \
  {                                                                             \
    unsigned _lo = (unsigned)__builtin_amdgcn_update_dpp(                       \
        0, (int)(unsigned)((vv) & 0xffffffffull), (ctrl), (rmask), 0xf, false); \
    unsigned _hi = (unsigned)__builtin_amdgcn_update_dpp(                       \
        0, (int)(unsigned)((vv) >> 32), (ctrl), (rmask), 0xf, false);           \
    unsigned long long _tv = ((unsigned long long)_hi << 32) | _lo;             \
    if (_tv > (vv)) (vv) = _tv;                                                 \
  }

// Exact-rounding distance^2, matching numpy: ((dx*dx + dy*dy) + dz*dz), no FMA.
__device__ __forceinline__ float dist2(float x, float y, float z,
                                       float cx, float cy, float cz) {
    float dx = __fsub_rn(x, cx);
    float dy = __fsub_rn(y, cy);
    float dz = __fsub_rn(z, cz);
    return __fadd_rn(__fadd_rn(__fmul_rn(dx, dx), __fmul_rn(dy, dy)),
                     __fmul_rn(dz, dz));
}

// ---------------------------------------------------------------------------
// Kernel 0: zero gl (ws is poisoned 0xAA; must be zeroed before group_kernel).
// ---------------------------------------------------------------------------
__global__ void init_kernel(int* __restrict__ gl) {
    int t = threadIdx.x;
    if (t < B_) gl[t] = 0;
}

// ---------------------------------------------------------------------------
// Kernel 1: FPS, ONE 1024-thread block per batch + fused CNMS.
//
// r12 post-mortem of r11: VGPR_Count=48 proved the compiler REMATERIALIZED the
// coordinate staging loads inside the k-loop (48 regs can't hold 48 coord +
// 16 mind VGPRs) => every step re-read 256KB/CU from L2 (~2000cyc) on top of
// the VALU work. FETCH_SIZE stayed ~1MB because the LLC absorbed it.
// Fix: PIN the staged registers with an empty asm "+v" barrier after staging.
// The values become opaque asm outputs => loads cannot be re-sunk; ~105 VGPRs
// total, still 4 waves/SIMD (cap 128).
// ---------------------------------------------------------------------------
__global__ __launch_bounds__(FPS_T, 4) void fps_cnms_kernel(
    const float4* __restrict__ pts, const int* __restrict__ lengths,
    float* __restrict__ centers_out, int* __restrict__ keep_out) {
    const int b = blockIdx.x;
    const int t = threadIdx.x;
    const int lane = t & 63;
    const int wv = t >> 6;
    const int len = lengths[b];
    const float4* p = pts + (size_t)b * N_;

    __shared__ __align__(16) unsigned long long s_part[2][FPS_W];
    __shared__ float s_cen[G_][3];                        // centers for CNMS

    // Stage all 16 points per thread into registers. Slot s (0..15) covers
    // n = s*1024 + t (ascending slot == ascending n, so strict > in the local
    // scan keeps the smallest index on ties).
    v2f xp[PPT / 2], yp[PPT / 2], zp[PPT / 2];
    float mind[PPT];
#pragma unroll
    for (int j = 0; j < PPT / 2; j++) {
        int nA = (2 * j) * FPS_T + t;
        int nB = nA + FPS_T;
        float4 qA = p[nA];
        float4 qB = p[nB];
        v2f xx, yy, zz;
        xx.x = qA.x; xx.y = qB.x;
        yy.x = qA.y; yy.y = qB.y;
        zz.x = qA.z; zz.y = qB.z;
        xp[j] = xx; yp[j] = yy; zp[j] = zz;
        mind[2 * j]     = (nA < len) ? INFINITY : -INFINITY;
        mind[2 * j + 1] = (nB < len) ? INFINITY : -INFINITY;
    }
    // PIN: make the staged coords opaque so the compiler cannot rematerialize
    // the global loads inside the k-loop (r11 failure mode, VGPR_Count=48).
#pragma unroll
    for (int j = 0; j < PPT / 2; j++) {
        asm volatile("" : "+v"(xp[j]), "+v"(yp[j]), "+v"(zp[j]));
    }

    int n = 0;   // winner index (uniform across the block)
    for (int k = 0; k < G_; k++) {
        float4 c = p[n];   // uniform broadcast load (L2-resident)
        if (t == 0) {
            centers_out[(b * G_ + k) * 3 + 0] = c.x;
            centers_out[(b * G_ + k) * 3 + 1] = c.y;
            centers_out[(b * G_ + k) * 3 + 2] = c.z;
            s_cen[k][0] = c.x; s_cen[k][1] = c.y; s_cen[k][2] = c.z;
        }
        if (k == G_ - 1) break;   // last argmax is discarded by the reference

        float ncx = -c.x, ncy = -c.y, ncz = -c.z;
        v2f cX, cY, cZ;
        cX.x = ncx; cX.y = ncx;
        cY.x = ncy; cY.y = ncy;
        cZ.x = ncz; cZ.y = ncz;

        float bv = -INFINITY;
        int bi = 0;                       // best point-slot 0..15 (inline consts)
#pragma unroll
        for (int j = 0; j < PPT / 2; j++) {
            v2f dx, dy, dz, qx, qy, qz, s0, d2v;
            PK_ADD(dx, xp[j], cX);        // x - cx (exact-neg trick)
            PK_ADD(dy, yp[j], cY);
            PK_ADD(dz, zp[j], cZ);
            PK_MUL(qx, dx, dx);
            PK_MUL(qy, dy, dy);
            PK_MUL(qz, dz, dz);
            PK_ADD(s0, qx, qy);           // (dx^2 + dy^2)
            PK_ADD(d2v, s0, qz);          // + dz^2   (reference order, no FMA)
            float mA = fminf(mind[2 * j],     d2v.x);
            float mB = fminf(mind[2 * j + 1], d2v.y);
            mind[2 * j] = mA;
            mind[2 * j + 1] = mB;
            if (mA > bv) { bv = mA; bi = 2 * j; }
            if (mB > bv) { bv = mB; bi = 2 * j + 1; }
        }

        // Monotone u32 key of bv (any non-NaN float, including +-inf).
        unsigned u = __float_as_uint(bv);
        u = (u & 0x80000000u) ? ~u : (u | 0x80000000u);
        int bn = (bi << 10) | t;          // global point index
        unsigned long long v = ((unsigned long long)u << 32) | (unsigned)(~bn);

        // Wave argmax: u64 max == (max value, then min index among ties).
        DPP64_MAXSTEP(v, 0x111, 0xf);     // row_shl 1
        DPP64_MAXSTEP(v, 0x112, 0xf);     // row_shl 2
        DPP64_MAXSTEP(v, 0x114, 0xf);     // row_shl 4
        DPP64_MAXSTEP(v, 0x118, 0xf);     // row_shl 8
        DPP64_MAXSTEP(v, 0x142, 0xa);     // row_bcast15
        DPP64_MAXSTEP(v, 0x143, 0xc);     // row_bcast31 -> lane63 has wave max
        if (lane == 63) s_part[k & 1][wv] = v;
        __syncthreads();

        // Every row of 16 lanes loads all 16 partials (same-address broadcast
        // across rows is free), reduces in 4 DPP steps, readlane(15) broadcasts.
        // Double-buffered s_part => one barrier per step is race-free.
        unsigned long long m = s_part[k & 1][lane & 15];
        DPP64_MAXSTEP(m, 0x111, 0xf);
        DPP64_MAXSTEP(m, 0x112, 0xf);
        DPP64_MAXSTEP(m, 0x114, 0xf);
        DPP64_MAXSTEP(m, 0x118, 0xf);
        unsigned wlo = (unsigned)__builtin_amdgcn_readlane(
            (int)(unsigned)(m & 0xffffffffull), 15);
        n = (int)(~wlo);                  // decode index
    }

    __syncthreads();   // s_cen[127] written by t==0 after the break

    // ---- fused CNMS on wave 0 ----
    if (t < 64) {
        const float THR = (float)((2.0 * 0.1 * (1.0 - 0.7)) * (2.0 * 0.1 * (1.0 - 0.7)));
        float ax = s_cen[t][0],      ay = s_cen[t][1],      az = s_cen[t][2];
        float ex = s_cen[t + 64][0], ey = s_cen[t + 64][1], ez = s_cen[t + 64][2];
        bool k0 = false, k1 = false;
        for (int j = 0; j < G_; j++) {
            float jx = s_cen[j][0], jy = s_cen[j][1], jz = s_cen[j][2];
            bool c0 = k0 && (dist2(ax, ay, az, jx, jy, jz) < THR);
            bool c1 = k1 && (dist2(ex, ey, ez, jx, jy, jz) < THR);
            bool conflict = __any(c0 || c1);
            if (j == t)      k0 = !conflict;
            if (j == t + 64) k1 = !conflict;
        }
        keep_out[b * G_ + t]      = k0 ? 1 : 0;
        keep_out[b * G_ + t + 64] = k1 ? 1 : 0;
    }
}

// ---------------------------------------------------------------------------
// Kernel 2: per-(b,g) ball query (first 128 by index) + top-32 by energy +
// gather/normalize. One 512-thread block per group. (unchanged)
// ---------------------------------------------------------------------------
__global__ __launch_bounds__(BQ_T) void group_kernel(
    const float4* __restrict__ pts, const int* __restrict__ lengths,
    const float* __restrict__ centers, const int* __restrict__ keep,
    float* __restrict__ groups_out, int* __restrict__ gl) {
    const int bid = blockIdx.x;          // b*128 + g
    const int b = bid >> 7;
    const int t = threadIdx.x;
    const int lane = t & 63;
    const int wv = t >> 6;

    const float cx = centers[bid * 3 + 0];
    const float cy = centers[bid * 3 + 1];
    const float cz = centers[bid * 3 + 2];
    float4* out4 = (float4*)(groups_out + (size_t)bid * GS_ * 4);

    if (!keep[bid]) {
        if (t < GS_) {
            float4 o;
            o.x = __fdiv_rn(__fsub_rn(0.f, cx), 0.1f);
            o.y = __fdiv_rn(__fsub_rn(0.f, cy), 0.1f);
            o.z = __fdiv_rn(__fsub_rn(0.f, cz), 0.1f);
            o.w = 0.f;
            out4[t] = o;
        }
        return;
    }

    __shared__ int   s_widx[BQ_W][UK_];
    __shared__ float s_wen[BQ_W][UK_];
    __shared__ int   s_wcnt[BQ_W];
    __shared__ int   s_list[UK_];
    __shared__ float s_en[UK_];
    __shared__ int   s_ord[GS_];

    const int len = lengths[b];
    const float R2 = (float)(0.1 * 0.1);
    const float4* p = pts + (size_t)b * N_;

    // Per-wave ordered stream compaction over its contiguous eighth.
    {
        const int base0 = wv * (N_ / BQ_W);
        int cnt = 0;
        for (int it = 0; it < (N_ / BQ_W) / 64; it++) {
            int n = base0 + it * 64 + lane;
            float4 q = p[n];
            float d2 = dist2(q.x, q.y, q.z, cx, cy, cz);
            bool pred = (n < len) && (d2 <= R2);
            unsigned long long m = __ballot(pred);
            int prefix = __popcll(m & ((1ull << lane) - 1ull));
            int slot = cnt + prefix;
            if (pred && slot < UK_) { s_widx[wv][slot] = n; s_wen[wv][slot] = q.w; }
            cnt += __popcll(m);
        }
        if (lane == 0) s_wcnt[wv] = (cnt < UK_) ? cnt : UK_;
    }
    __syncthreads();

    int M = 0;
#pragma unroll
    for (int w = 0; w < BQ_W; w++) M += s_wcnt[w];
    if (M > UK_) M = UK_;

    // Ordered merge into unified first-M list.
    if (t < UK_ && t < M) {
        int j = t, w = 0;
        while (w < BQ_W - 1 && j >= s_wcnt[w]) { j -= s_wcnt[w]; w++; }
        s_list[t] = s_widx[w][j];
        s_en[t]   = s_wen[w][j];
    }
    __syncthreads();

    // top-32 by energy, tie -> smaller list position (matches lax.top_k)
    if (wv == 0) {
        float v0 = (lane < M) ? s_en[lane] : -INFINITY;
        float v1 = (lane + 64 < M) ? s_en[lane + 64] : -INFINITY;
        for (int k = 0; k < GS_; k++) {
            float bv; int bs;
            if (v0 >= v1) { bv = v0; bs = lane; }
            else          { bv = v1; bs = lane + 64; }
#pragma unroll
            for (int off = 32; off; off >>= 1) {
                float ov = __shfl_xor(bv, off);
                int   os = __shfl_xor(bs, off);
                bool tk = (ov > bv) || (ov == bv && os < bs);
                bv = tk ? ov : bv; bs = tk ? os : bs;
            }
            if (lane == 0) s_ord[k] = (bv == -INFINITY) ? -1 : bs;
            if (bs == lane)           v0 = -INFINITY;
            else if (bs == lane + 64) v1 = -INFINITY;
        }
    }
    __syncthreads();

    if (t < GS_) {
        int o0 = s_ord[0];
        int first = (o0 >= 0) ? s_list[o0] : -1;
        int ok = s_ord[t];
        int ti = (ok >= 0) ? s_list[ok] : -1;
        int f = (ti == -1) ? first : ti;
        float px = 0.f, py = 0.f, pz = 0.f, pw = 0.f;
        if (f >= 0) { float4 q = p[f]; px = q.x; py = q.y; pz = q.z; pw = q.w; }
        float4 o;
        o.x = __fdiv_rn(__fsub_rn(px, cx), 0.1f);
        o.y = __fdiv_rn(__fsub_rn(py, cy), 0.1f);
        o.z = __fdiv_rn(__fsub_rn(pz, cz), 0.1f);
        o.w = __fdiv_rn(pw, 0.1f);
        out4[t] = o;
    }
    if (t == 0 && M >= GS_) atomicAdd(&gl[b], 1);
}

// ---------------------------------------------------------------------------
// Kernel 3: embedding mask
// ---------------------------------------------------------------------------
__global__ void mask_kernel(const int* __restrict__ gl, float* __restrict__ mask_out) {
    int t = threadIdx.x;                 // 1024 threads
    int b = t >> 7, g = t & 127;
    mask_out[t] = (g < gl[b]) ? 1.0f : 0.0f;
}

extern "C" void kernel_launch(void* const* d_in, const int* in_sizes, int n_in,
                              void* d_out, int out_size, void* d_ws, size_t ws_size,
                              hipStream_t stream) {
    const float4* pts = (const float4*)d_in[0];
    const int* lengths = (const int*)d_in[1];
    float* out = (float*)d_out;
    float* groups = out;                               // B*G*GS*4 = 131072
    float* centers = out + (size_t)B_ * G_ * GS_ * 4;  // +3072
    float* mask = centers + (size_t)B_ * G_ * 3;       // +1024
    int* keep = (int*)d_ws;                            // B*G ints
    int* gl = keep + B_ * G_;                          // B ints

    hipLaunchKernelGGL(init_kernel, dim3(1), dim3(64), 0, stream, gl);
    hipLaunchKernelGGL(fps_cnms_kernel, dim3(B_), dim3(FPS_T), 0, stream,
                       pts, lengths, centers, keep);
    hipLaunchKernelGGL(group_kernel, dim3(B_ * G_), dim3(BQ_T), 0, stream,
                       pts, lengths, centers, keep, groups, gl);
    hipLaunchKernelGGL(mask_kernel, dim3(1), dim3(B_ * G_), 0, stream, gl, mask);
}

// Round 4
// 337.243 us; speedup vs baseline: 1.0296x; 1.0296x over previous
//
#include <hip/hip_runtime.h>
#include <math.h>

#define B_ 8
#define N_ 16384
#define G_ 128      // NUM_GROUPS
#define GS_ 32      // GROUP_SIZE
#define UK_ 128     // UPSCALE_K
#define FPS_T 1024
#define FPS_W 16    // waves per FPS block
#define PPT 16      // points per thread (N_ / FPS_T)
#define BQ_T 512
#define BQ_W 8      // waves per group block

typedef float v2f __attribute__((ext_vector_type(2)));

// Packed fp32 ops (VOP3P). Same IEEE rounding as scalar v_add/v_mul per lane.
// Subtraction is x + (-c): negation is exact, so rounding matches x - c.
#define PK_ADD(d, a, b) asm("v_pk_add_f32 %0, %1, %2" : "=v"(d) : "v"(a), "v"(b))
#define PK_MUL(d, a, b) asm("v_pk_mul_f32 %0, %1, %2" : "=v"(d) : "v"(a), "v"(b))

// 64-bit max-combine with a DPP-shifted copy of vv (old=0 == identity for max).
#define DPP64_MAXSTEP(vv, ctrl, rmask)                                          \
  {                                                                             \
    unsigned _lo = (unsigned)__builtin_amdgcn_update_dpp(                       \
        0, (int)(unsigned)((vv) & 0xffffffffull), (ctrl), (rmask), 0xf, false); \
    unsigned _hi = (unsigned)__builtin_amdgcn_update_dpp(                       \
        0, (int)(unsigned)((vv) >> 32), (ctrl), (rmask), 0xf, false);           \
    unsigned long long _tv = ((unsigned long long)_hi << 32) | _lo;             \
    if (_tv > (vv)) (vv) = _tv;                                                 \
  }

// Exact-rounding distance^2, matching numpy: ((dx*dx + dy*dy) + dz*dz), no FMA.
__device__ __forceinline__ float dist2(float x, float y, float z,
                                       float cx, float cy, float cz) {
    float dx = __fsub_rn(x, cx);
    float dy = __fsub_rn(y, cy);
    float dz = __fsub_rn(z, cz);
    return __fadd_rn(__fadd_rn(__fmul_rn(dx, dx), __fmul_rn(dy, dy)),
                     __fmul_rn(dz, dz));
}

// ---------------------------------------------------------------------------
// Kernel 0: zero gl (ws is poisoned 0xAA; must be zeroed before group_kernel).
// ---------------------------------------------------------------------------
__global__ void init_kernel(int* __restrict__ gl) {
    int t = threadIdx.x;
    if (t < B_) gl[t] = 0;
}

// ---------------------------------------------------------------------------
// Kernel 1: FPS, ONE 1024-thread block per batch + fused CNMS.
//
// Structure (r13, refined r14): register residence of the coords is not
// reliably expressible (r11/r12: RA remats the staging loads, VGPR=48), so
// xy of ALL 16384 points lives in 128KB LDS; z + running min-dist in regs
// (~35 payload regs). One block per batch => no cross-CU merge.
// r14: lane-parallel packing (xA,xB)/(yA,yB)/(zA,zB) => distance of 2 points
// is 8 packed VOP3P ops, no horizontal adds; argmax deferred out of the inner
// loop (min-only inner loop, post-loop fmax tree + descending index scan).
// Bit-exact: per-lane order ((dx^2+dy^2)+dz^2), ties -> smallest n.
// ---------------------------------------------------------------------------
__global__ __launch_bounds__(FPS_T, 4) void fps_cnms_kernel(
    const float4* __restrict__ pts, const int* __restrict__ lengths,
    float* __restrict__ centers_out, int* __restrict__ keep_out) {
    const int b = blockIdx.x;
    const int t = threadIdx.x;
    const int lane = t & 63;
    const int wv = t >> 6;
    const int len = lengths[b];
    const float4* p = pts + (size_t)b * N_;

    __shared__ float4 s_xy4[N_ / 2];                      // 128 KB: (xA,xB,yA,yB)
    __shared__ __align__(16) unsigned long long s_part[2][FPS_W];
    __shared__ float s_cen[G_][3];                        // centers for CNMS

    // Stage xy pairs -> LDS; z + running min-dist in registers. Pair j covers
    // nA = (2j)*1024+t and nB = (2j+1)*1024+t.
    v2f zp[PPT / 2];
    v2f mp[PPT / 2];
#pragma unroll
    for (int j = 0; j < PPT / 2; j++) {
        int nA = (2 * j) * FPS_T + t;
        int nB = nA + FPS_T;
        float4 qA = p[nA];
        float4 qB = p[nB];
        s_xy4[j * FPS_T + t] = make_float4(qA.x, qB.x, qA.y, qB.y);
        v2f zz; zz.x = qA.z; zz.y = qB.z;
        zp[j] = zz;
        v2f mm;
        mm.x = (nA < len) ? INFINITY : -INFINITY;
        mm.y = (nB < len) ? INFINITY : -INFINITY;
        mp[j] = mm;
    }
    // Pin z so the RA has no incentive to re-derive it from global loads.
#pragma unroll
    for (int j = 0; j < PPT / 2; j++) asm volatile("" : "+v"(zp[j]));
    __syncthreads();

    int n = 0;   // winner index (uniform across the block)
    for (int k = 0; k < G_; k++) {
        float4 c = p[n];   // uniform broadcast load (L2-resident)
        if (t == 0) {
            centers_out[(b * G_ + k) * 3 + 0] = c.x;
            centers_out[(b * G_ + k) * 3 + 1] = c.y;
            centers_out[(b * G_ + k) * 3 + 2] = c.z;
            s_cen[k][0] = c.x; s_cen[k][1] = c.y; s_cen[k][2] = c.z;
        }
        if (k == G_ - 1) break;   // last argmax is discarded by the reference

        v2f cXX, cYY, cZZ;
        cXX.x = -c.x; cXX.y = -c.x;
        cYY.x = -c.y; cYY.y = -c.y;
        cZZ.x = -c.z; cZZ.y = -c.z;

        // Min-only inner loop: 8 packed VOP3P + 2 v_min per point-pair.
#pragma unroll
        for (int j = 0; j < PPT / 2; j++) {
            float4 xy = s_xy4[j * FPS_T + t];             // ds_read_b128, 2 pts
            v2f xv, yv;
            xv.x = xy.x; xv.y = xy.y;                     // (xA, xB)
            yv.x = xy.z; yv.y = xy.w;                     // (yA, yB)
            v2f dx, dy, dz, qx, qy, qz, s0, d2v;
            PK_ADD(dx, xv, cXX);          // x - cx (exact-neg trick)
            PK_ADD(dy, yv, cYY);
            PK_ADD(dz, zp[j], cZZ);
            PK_MUL(qx, dx, dx);
            PK_MUL(qy, dy, dy);
            PK_MUL(qz, dz, dz);
            PK_ADD(s0, qx, qy);           // (dx^2 + dy^2)
            PK_ADD(d2v, s0, qz);          // + dz^2   (per-lane reference order)
            mp[j].x = fminf(mp[j].x, d2v.x);
            mp[j].y = fminf(mp[j].y, d2v.y);
        }

        // Deferred thread-local argmax over the 16 mind values.
        float bv = mp[0].x;
#pragma unroll
        for (int j = 0; j < PPT / 2; j++) {
            if (j > 0) bv = fmaxf(bv, mp[j].x);
            bv = fmaxf(bv, mp[j].y);
        }
        int bi = 0;   // smallest slot holding bv (slot s covers n = s*1024+t)
#pragma unroll
        for (int s = PPT - 1; s >= 0; s--) {
            float mv = (s & 1) ? mp[s >> 1].y : mp[s >> 1].x;
            if (mv == bv) bi = s;
        }

        // Monotone u32 key of bv (any non-NaN float, including +-inf).
        unsigned u = __float_as_uint(bv);
        u = (u & 0x80000000u) ? ~u : (u | 0x80000000u);
        int bn = (bi << 10) | t;          // global point index
        unsigned long long v = ((unsigned long long)u << 32) | (unsigned)(~bn);

        // Wave argmax: u64 max == (max value, then min index among ties).
        DPP64_MAXSTEP(v, 0x111, 0xf);     // row_shl 1
        DPP64_MAXSTEP(v, 0x112, 0xf);     // row_shl 2
        DPP64_MAXSTEP(v, 0x114, 0xf);     // row_shl 4
        DPP64_MAXSTEP(v, 0x118, 0xf);     // row_shl 8
        DPP64_MAXSTEP(v, 0x142, 0xa);     // row_bcast15
        DPP64_MAXSTEP(v, 0x143, 0xc);     // row_bcast31 -> lane63 has wave max
        if (lane == 63) s_part[k & 1][wv] = v;
        __syncthreads();

        // Each 16-lane row reads all 16 partials (same-address broadcast across
        // rows is free), reduces in 4 DPP steps, readlane(15) broadcasts.
        // Double-buffered s_part => one barrier per step is race-free.
        unsigned long long m = s_part[k & 1][lane & 15];
        DPP64_MAXSTEP(m, 0x111, 0xf);
        DPP64_MAXSTEP(m, 0x112, 0xf);
        DPP64_MAXSTEP(m, 0x114, 0xf);
        DPP64_MAXSTEP(m, 0x118, 0xf);
        unsigned wlo = (unsigned)__builtin_amdgcn_readlane(
            (int)(unsigned)(m & 0xffffffffull), 15);
        n = (int)(~wlo);                  // decode index
    }

    __syncthreads();   // s_cen[127] written by t==0 after the break

    // ---- fused CNMS on wave 0 ----
    if (t < 64) {
        const float THR = (float)((2.0 * 0.1 * (1.0 - 0.7)) * (2.0 * 0.1 * (1.0 - 0.7)));
        float ax = s_cen[t][0],      ay = s_cen[t][1],      az = s_cen[t][2];
        float ex = s_cen[t + 64][0], ey = s_cen[t + 64][1], ez = s_cen[t + 64][2];
        bool k0 = false, k1 = false;
        for (int j = 0; j < G_; j++) {
            float jx = s_cen[j][0], jy = s_cen[j][1], jz = s_cen[j][2];
            bool c0 = k0 && (dist2(ax, ay, az, jx, jy, jz) < THR);
            bool c1 = k1 && (dist2(ex, ey, ez, jx, jy, jz) < THR);
            bool conflict = __any(c0 || c1);
            if (j == t)      k0 = !conflict;
            if (j == t + 64) k1 = !conflict;
        }
        keep_out[b * G_ + t]      = k0 ? 1 : 0;
        keep_out[b * G_ + t + 64] = k1 ? 1 : 0;
    }
}

// ---------------------------------------------------------------------------
// Kernel 2: per-(b,g) ball query (first 128 by index) + top-32 by energy +
// gather/normalize. One 512-thread block per group. (unchanged)
// ---------------------------------------------------------------------------
__global__ __launch_bounds__(BQ_T) void group_kernel(
    const float4* __restrict__ pts, const int* __restrict__ lengths,
    const float* __restrict__ centers, const int* __restrict__ keep,
    float* __restrict__ groups_out, int* __restrict__ gl) {
    const int bid = blockIdx.x;          // b*128 + g
    const int b = bid >> 7;
    const int t = threadIdx.x;
    const int lane = t & 63;
    const int wv = t >> 6;

    const float cx = centers[bid * 3 + 0];
    const float cy = centers[bid * 3 + 1];
    const float cz = centers[bid * 3 + 2];
    float4* out4 = (float4*)(groups_out + (size_t)bid * GS_ * 4);

    if (!keep[bid]) {
        if (t < GS_) {
            float4 o;
            o.x = __fdiv_rn(__fsub_rn(0.f, cx), 0.1f);
            o.y = __fdiv_rn(__fsub_rn(0.f, cy), 0.1f);
            o.z = __fdiv_rn(__fsub_rn(0.f, cz), 0.1f);
            o.w = 0.f;
            out4[t] = o;
        }
        return;
    }

    __shared__ int   s_widx[BQ_W][UK_];
    __shared__ float s_wen[BQ_W][UK_];
    __shared__ int   s_wcnt[BQ_W];
    __shared__ int   s_list[UK_];
    __shared__ float s_en[UK_];
    __shared__ int   s_ord[GS_];

    const int len = lengths[b];
    const float R2 = (float)(0.1 * 0.1);
    const float4* p = pts + (size_t)b * N_;

    // Per-wave ordered stream compaction over its contiguous eighth.
    {
        const int base0 = wv * (N_ / BQ_W);
        int cnt = 0;
        for (int it = 0; it < (N_ / BQ_W) / 64; it++) {
            int n = base0 + it * 64 + lane;
            float4 q = p[n];
            float d2 = dist2(q.x, q.y, q.z, cx, cy, cz);
            bool pred = (n < len) && (d2 <= R2);
            unsigned long long m = __ballot(pred);
            int prefix = __popcll(m & ((1ull << lane) - 1ull));
            int slot = cnt + prefix;
            if (pred && slot < UK_) { s_widx[wv][slot] = n; s_wen[wv][slot] = q.w; }
            cnt += __popcll(m);
        }
        if (lane == 0) s_wcnt[wv] = (cnt < UK_) ? cnt : UK_;
    }
    __syncthreads();

    int M = 0;
#pragma unroll
    for (int w = 0; w < BQ_W; w++) M += s_wcnt[w];
    if (M > UK_) M = UK_;

    // Ordered merge into unified first-M list.
    if (t < UK_ && t < M) {
        int j = t, w = 0;
        while (w < BQ_W - 1 && j >= s_wcnt[w]) { j -= s_wcnt[w]; w++; }
        s_list[t] = s_widx[w][j];
        s_en[t]   = s_wen[w][j];
    }
    __syncthreads();

    // top-32 by energy, tie -> smaller list position (matches lax.top_k)
    if (wv == 0) {
        float v0 = (lane < M) ? s_en[lane] : -INFINITY;
        float v1 = (lane + 64 < M) ? s_en[lane + 64] : -INFINITY;
        for (int k = 0; k < GS_; k++) {
            float bv; int bs;
            if (v0 >= v1) { bv = v0; bs = lane; }
            else          { bv = v1; bs = lane + 64; }
#pragma unroll
            for (int off = 32; off; off >>= 1) {
                float ov = __shfl_xor(bv, off);
                int   os = __shfl_xor(bs, off);
                bool tk = (ov > bv) || (ov == bv && os < bs);
                bv = tk ? ov : bv; bs = tk ? os : bs;
            }
            if (lane == 0) s_ord[k] = (bv == -INFINITY) ? -1 : bs;
            if (bs == lane)           v0 = -INFINITY;
            else if (bs == lane + 64) v1 = -INFINITY;
        }
    }
    __syncthreads();

    if (t < GS_) {
        int o0 = s_ord[0];
        int first = (o0 >= 0) ? s_list[o0] : -1;
        int ok = s_ord[t];
        int ti = (ok >= 0) ? s_list[ok] : -1;
        int f = (ti == -1) ? first : ti;
        float px = 0.f, py = 0.f, pz = 0.f, pw = 0.f;
        if (f >= 0) { float4 q = p[f]; px = q.x; py = q.y; pz = q.z; pw = q.w; }
        float4 o;
        o.x = __fdiv_rn(__fsub_rn(px, cx), 0.1f);
        o.y = __fdiv_rn(__fsub_rn(py, cy), 0.1f);
        o.z = __fdiv_rn(__fsub_rn(pz, cz), 0.1f);
        o.w = __fdiv_rn(pw, 0.1f);
        out4[t] = o;
    }
    if (t == 0 && M >= GS_) atomicAdd(&gl[b], 1);
}

// ---------------------------------------------------------------------------
// Kernel 3: embedding mask
// ---------------------------------------------------------------------------
__global__ void mask_kernel(const int* __restrict__ gl, float* __restrict__ mask_out) {
    int t = threadIdx.x;                 // 1024 threads
    int b = t >> 7, g = t & 127;
    mask_out[t] = (g < gl[b]) ? 1.0f : 0.0f;
}

extern "C" void kernel_launch(void* const* d_in, const int* in_sizes, int n_in,
                              void* d_out, int out_size, void* d_ws, size_t ws_size,
                              hipStream_t stream) {
    const float4* pts = (const float4*)d_in[0];
    const int* lengths = (const int*)d_in[1];
    float* out = (float*)d_out;
    float* groups = out;                               // B*G*GS*4 = 131072
    float* centers = out + (size_t)B_ * G_ * GS_ * 4;  // +3072
    float* mask = centers + (size_t)B_ * G_ * 3;       // +1024
    int* keep = (int*)d_ws;                            // B*G ints
    int* gl = keep + B_ * G_;                          // B ints

    hipLaunchKernelGGL(init_kernel, dim3(1), dim3(64), 0, stream, gl);
    hipLaunchKernelGGL(fps_cnms_kernel, dim3(B_), dim3(FPS_T), 0, stream,
                       pts, lengths, centers, keep);
    hipLaunchKernelGGL(group_kernel, dim3(B_ * G_), dim3(BQ_T), 0, stream,
                       pts, lengths, centers, keep, groups, gl);
    hipLaunchKernelGGL(mask_kernel, dim3(1), dim3(B_ * G_), 0, stream, gl, mask);
}

// Round 5
// 318.625 us; speedup vs baseline: 1.0897x; 1.0584x over previous
//
#include <hip/hip_runtime.h>
#include <math.h>

#define B_ 8
#define N_ 16384
#define G_ 128      // NUM_GROUPS
#define GS_ 32      // GROUP_SIZE
#define UK_ 128     // UPSCALE_K
#define FPS_T 1024
#define FPS_W 16    // waves per FPS block
#define PPT 16      // points per thread (N_ / FPS_T)
#define BQ_T 512
#define BQ_W 8      // waves per group block

// No mul+add contraction anywhere in this TU: per-op IEEE rounding must match
// the numpy reference exactly (((dx*dx + dy*dy) + dz*dz), each op rounded).
#pragma clang fp contract(off)

typedef float v2f __attribute__((ext_vector_type(2)));

// 64-bit max-combine with a DPP-shifted copy of vv (old=0 == identity for max).
#define DPP64_MAXSTEP(vv, ctrl, rmask)                                          \
  {                                                                             \
    unsigned _lo = (unsigned)__builtin_amdgcn_update_dpp(                       \
        0, (int)(unsigned)((vv) & 0xffffffffull), (ctrl), (rmask), 0xf, false); \
    unsigned _hi = (unsigned)__builtin_amdgcn_update_dpp(                       \
        0, (int)(unsigned)((vv) >> 32), (ctrl), (rmask), 0xf, false);           \
    unsigned long long _tv = ((unsigned long long)_hi << 32) | _lo;             \
    if (_tv > (vv)) (vv) = _tv;                                                 \
  }

// Exact-rounding distance^2, matching numpy: ((dx*dx + dy*dy) + dz*dz), no FMA.
__device__ __forceinline__ float dist2(float x, float y, float z,
                                       float cx, float cy, float cz) {
    float dx = __fsub_rn(x, cx);
    float dy = __fsub_rn(y, cy);
    float dz = __fsub_rn(z, cz);
    return __fadd_rn(__fadd_rn(__fmul_rn(dx, dx), __fmul_rn(dy, dy)),
                     __fmul_rn(dz, dz));
}

// ---------------------------------------------------------------------------
// Kernel 0: zero gl (ws is poisoned 0xAA; must be zeroed before group_kernel).
// ---------------------------------------------------------------------------
__global__ void init_kernel(int* __restrict__ gl) {
    int t = threadIdx.x;
    if (t < B_) gl[t] = 0;
}

// ---------------------------------------------------------------------------
// Kernel 1: FPS, ONE 1024-thread block per batch + fused CNMS.
//
// r15 post-mortem of r14: derived % are device-normalized => the 8 active CUs
// were ~80% VALU-busy (2.5% x 256/8). 4700cyc/step implies ~470 VALU
// instr/thread/step, ~2x the source count. Culprit: inline-asm PK ops — "v"
// constraints on v2f force mov-pairs around each of 64 opaque asm blocks
// (~+180 instr/step). Fix: native v2f arithmetic under fp contract(off); the
// backend emits v_pk_add/mul_f32 (sub = pk_add w/ neg modifier) with free
// scheduling, no movs. Rounding per lane unchanged: ((dx^2+dy^2)+dz^2), rn.
// Structure unchanged: xy of all 16384 pts in 128KB LDS, z+mind in regs,
// one block per batch (no cross-CU merge), u64 DPP argmax ladders.
// ---------------------------------------------------------------------------
__global__ __launch_bounds__(FPS_T, 4) void fps_cnms_kernel(
    const float4* __restrict__ pts, const int* __restrict__ lengths,
    float* __restrict__ centers_out, int* __restrict__ keep_out) {
    const int b = blockIdx.x;
    const int t = threadIdx.x;
    const int lane = t & 63;
    const int wv = t >> 6;
    const int len = lengths[b];
    const float4* p = pts + (size_t)b * N_;

    __shared__ float4 s_xy4[N_ / 2];                      // 128 KB: (xA,xB,yA,yB)
    __shared__ __align__(16) unsigned long long s_part[2][FPS_W];
    __shared__ float s_cen[G_][3];                        // centers for CNMS

    // Stage xy pairs -> LDS; z + running min-dist in registers. Pair j covers
    // nA = (2j)*1024+t and nB = (2j+1)*1024+t.
    v2f zp[PPT / 2];
    v2f mp[PPT / 2];
#pragma unroll
    for (int j = 0; j < PPT / 2; j++) {
        int nA = (2 * j) * FPS_T + t;
        int nB = nA + FPS_T;
        float4 qA = p[nA];
        float4 qB = p[nB];
        s_xy4[j * FPS_T + t] = make_float4(qA.x, qB.x, qA.y, qB.y);
        v2f zz; zz.x = qA.z; zz.y = qB.z;
        zp[j] = zz;
        v2f mm;
        mm.x = (nA < len) ? INFINITY : -INFINITY;
        mm.y = (nB < len) ? INFINITY : -INFINITY;
        mp[j] = mm;
    }
    // Pin z so the RA has no incentive to re-derive it from global loads.
#pragma unroll
    for (int j = 0; j < PPT / 2; j++) asm volatile("" : "+v"(zp[j]));
    __syncthreads();

    int n = 0;   // winner index (uniform across the block)
    for (int k = 0; k < G_; k++) {
        float4 c = p[n];   // uniform broadcast load (L2-resident)
        if (t == 0) {
            centers_out[(b * G_ + k) * 3 + 0] = c.x;
            centers_out[(b * G_ + k) * 3 + 1] = c.y;
            centers_out[(b * G_ + k) * 3 + 2] = c.z;
            s_cen[k][0] = c.x; s_cen[k][1] = c.y; s_cen[k][2] = c.z;
        }
        if (k == G_ - 1) break;   // last argmax is discarded by the reference

        v2f cXX, cYY, cZZ;
        cXX.x = c.x; cXX.y = c.x;
        cYY.x = c.y; cYY.y = c.y;
        cZZ.x = c.z; cZZ.y = c.z;

        // Min-only inner loop, native v2f ops (v_pk_*): 8 pk + 2 min per pair.
#pragma unroll
        for (int j = 0; j < PPT / 2; j++) {
            float4 xy = s_xy4[j * FPS_T + t];             // ds_read_b128, 2 pts
            v2f xv, yv;
            xv.x = xy.x; xv.y = xy.y;                     // (xA, xB)
            yv.x = xy.z; yv.y = xy.w;                     // (yA, yB)
            v2f dx = xv - cXX;
            v2f dy = yv - cYY;
            v2f dz = zp[j] - cZZ;
            v2f dd = (dx * dx + dy * dy) + dz * dz;       // contract(off): exact
            mp[j].x = fminf(mp[j].x, dd.x);
            mp[j].y = fminf(mp[j].y, dd.y);
        }

        // Deferred thread-local argmax over the 16 mind values.
        float bv = mp[0].x;
#pragma unroll
        for (int j = 0; j < PPT / 2; j++) {
            if (j > 0) bv = fmaxf(bv, mp[j].x);
            bv = fmaxf(bv, mp[j].y);
        }
        int bi = 0;   // smallest slot holding bv (slot s covers n = s*1024+t)
#pragma unroll
        for (int s = PPT - 1; s >= 0; s--) {
            float mv = (s & 1) ? mp[s >> 1].y : mp[s >> 1].x;
            if (mv == bv) bi = s;
        }

        // Monotone u32 key of bv (any non-NaN float, including +-inf).
        unsigned u = __float_as_uint(bv);
        u = (u & 0x80000000u) ? ~u : (u | 0x80000000u);
        int bn = (bi << 10) | t;          // global point index
        unsigned long long v = ((unsigned long long)u << 32) | (unsigned)(~bn);

        // Wave argmax: u64 max == (max value, then min index among ties).
        DPP64_MAXSTEP(v, 0x111, 0xf);     // row_shl 1
        DPP64_MAXSTEP(v, 0x112, 0xf);     // row_shl 2
        DPP64_MAXSTEP(v, 0x114, 0xf);     // row_shl 4
        DPP64_MAXSTEP(v, 0x118, 0xf);     // row_shl 8
        DPP64_MAXSTEP(v, 0x142, 0xa);     // row_bcast15
        DPP64_MAXSTEP(v, 0x143, 0xc);     // row_bcast31 -> lane63 has wave max
        if (lane == 63) s_part[k & 1][wv] = v;
        __syncthreads();

        // Each 16-lane row reads all 16 partials (same-address broadcast across
        // rows is free), reduces in 4 DPP steps, readlane(15) broadcasts.
        // Double-buffered s_part => one barrier per step is race-free.
        unsigned long long m = s_part[k & 1][lane & 15];
        DPP64_MAXSTEP(m, 0x111, 0xf);
        DPP64_MAXSTEP(m, 0x112, 0xf);
        DPP64_MAXSTEP(m, 0x114, 0xf);
        DPP64_MAXSTEP(m, 0x118, 0xf);
        unsigned wlo = (unsigned)__builtin_amdgcn_readlane(
            (int)(unsigned)(m & 0xffffffffull), 15);
        n = (int)(~wlo);                  // decode index
    }

    __syncthreads();   // s_cen[127] written by t==0 after the break

    // ---- fused CNMS on wave 0 ----
    if (t < 64) {
        const float THR = (float)((2.0 * 0.1 * (1.0 - 0.7)) * (2.0 * 0.1 * (1.0 - 0.7)));
        float ax = s_cen[t][0],      ay = s_cen[t][1],      az = s_cen[t][2];
        float ex = s_cen[t + 64][0], ey = s_cen[t + 64][1], ez = s_cen[t + 64][2];
        bool k0 = false, k1 = false;
        for (int j = 0; j < G_; j++) {
            float jx = s_cen[j][0], jy = s_cen[j][1], jz = s_cen[j][2];
            bool c0 = k0 && (dist2(ax, ay, az, jx, jy, jz) < THR);
            bool c1 = k1 && (dist2(ex, ey, ez, jx, jy, jz) < THR);
            bool conflict = __any(c0 || c1);
            if (j == t)      k0 = !conflict;
            if (j == t + 64) k1 = !conflict;
        }
        keep_out[b * G_ + t]      = k0 ? 1 : 0;
        keep_out[b * G_ + t + 64] = k1 ? 1 : 0;
    }
}

// ---------------------------------------------------------------------------
// Kernel 2: per-(b,g) ball query (first 128 by index) + top-32 by energy +
// gather/normalize. One 512-thread block per group. (unchanged)
// ---------------------------------------------------------------------------
__global__ __launch_bounds__(BQ_T) void group_kernel(
    const float4* __restrict__ pts, const int* __restrict__ lengths,
    const float* __restrict__ centers, const int* __restrict__ keep,
    float* __restrict__ groups_out, int* __restrict__ gl) {
    const int bid = blockIdx.x;          // b*128 + g
    const int b = bid >> 7;
    const int t = threadIdx.x;
    const int lane = t & 63;
    const int wv = t >> 6;

    const float cx = centers[bid * 3 + 0];
    const float cy = centers[bid * 3 + 1];
    const float cz = centers[bid * 3 + 2];
    float4* out4 = (float4*)(groups_out + (size_t)bid * GS_ * 4);

    if (!keep[bid]) {
        if (t < GS_) {
            float4 o;
            o.x = __fdiv_rn(__fsub_rn(0.f, cx), 0.1f);
            o.y = __fdiv_rn(__fsub_rn(0.f, cy), 0.1f);
            o.z = __fdiv_rn(__fsub_rn(0.f, cz), 0.1f);
            o.w = 0.f;
            out4[t] = o;
        }
        return;
    }

    __shared__ int   s_widx[BQ_W][UK_];
    __shared__ float s_wen[BQ_W][UK_];
    __shared__ int   s_wcnt[BQ_W];
    __shared__ int   s_list[UK_];
    __shared__ float s_en[UK_];
    __shared__ int   s_ord[GS_];

    const int len = lengths[b];
    const float R2 = (float)(0.1 * 0.1);
    const float4* p = pts + (size_t)b * N_;

    // Per-wave ordered stream compaction over its contiguous eighth.
    {
        const int base0 = wv * (N_ / BQ_W);
        int cnt = 0;
        for (int it = 0; it < (N_ / BQ_W) / 64; it++) {
            int n = base0 + it * 64 + lane;
            float4 q = p[n];
            float d2 = dist2(q.x, q.y, q.z, cx, cy, cz);
            bool pred = (n < len) && (d2 <= R2);
            unsigned long long m = __ballot(pred);
            int prefix = __popcll(m & ((1ull << lane) - 1ull));
            int slot = cnt + prefix;
            if (pred && slot < UK_) { s_widx[wv][slot] = n; s_wen[wv][slot] = q.w; }
            cnt += __popcll(m);
        }
        if (lane == 0) s_wcnt[wv] = (cnt < UK_) ? cnt : UK_;
    }
    __syncthreads();

    int M = 0;
#pragma unroll
    for (int w = 0; w < BQ_W; w++) M += s_wcnt[w];
    if (M > UK_) M = UK_;

    // Ordered merge into unified first-M list.
    if (t < UK_ && t < M) {
        int j = t, w = 0;
        while (w < BQ_W - 1 && j >= s_wcnt[w]) { j -= s_wcnt[w]; w++; }
        s_list[t] = s_widx[w][j];
        s_en[t]   = s_wen[w][j];
    }
    __syncthreads();

    // top-32 by energy, tie -> smaller list position (matches lax.top_k)
    if (wv == 0) {
        float v0 = (lane < M) ? s_en[lane] : -INFINITY;
        float v1 = (lane + 64 < M) ? s_en[lane + 64] : -INFINITY;
        for (int k = 0; k < GS_; k++) {
            float bv; int bs;
            if (v0 >= v1) { bv = v0; bs = lane; }
            else          { bv = v1; bs = lane + 64; }
#pragma unroll
            for (int off = 32; off; off >>= 1) {
                float ov = __shfl_xor(bv, off);
                int   os = __shfl_xor(bs, off);
                bool tk = (ov > bv) || (ov == bv && os < bs);
                bv = tk ? ov : bv; bs = tk ? os : bs;
            }
            if (lane == 0) s_ord[k] = (bv == -INFINITY) ? -1 : bs;
            if (bs == lane)           v0 = -INFINITY;
            else if (bs == lane + 64) v1 = -INFINITY;
        }
    }
    __syncthreads();

    if (t < GS_) {
        int o0 = s_ord[0];
        int first = (o0 >= 0) ? s_list[o0] : -1;
        int ok = s_ord[t];
        int ti = (ok >= 0) ? s_list[ok] : -1;
        int f = (ti == -1) ? first : ti;
        float px = 0.f, py = 0.f, pz = 0.f, pw = 0.f;
        if (f >= 0) { float4 q = p[f]; px = q.x; py = q.y; pz = q.z; pw = q.w; }
        float4 o;
        o.x = __fdiv_rn(__fsub_rn(px, cx), 0.1f);
        o.y = __fdiv_rn(__fsub_rn(py, cy), 0.1f);
        o.z = __fdiv_rn(__fsub_rn(pz, cz), 0.1f);
        o.w = __fdiv_rn(pw, 0.1f);
        out4[t] = o;
    }
    if (t == 0 && M >= GS_) atomicAdd(&gl[b], 1);
}

// ---------------------------------------------------------------------------
// Kernel 3: embedding mask
// ---------------------------------------------------------------------------
__global__ void mask_kernel(const int* __restrict__ gl, float* __restrict__ mask_out) {
    int t = threadIdx.x;                 // 1024 threads
    int b = t >> 7, g = t & 127;
    mask_out[t] = (g < gl[b]) ? 1.0f : 0.0f;
}

extern "C" void kernel_launch(void* const* d_in, const int* in_sizes, int n_in,
                              void* d_out, int out_size, void* d_ws, size_t ws_size,
                              hipStream_t stream) {
    const float4* pts = (const float4*)d_in[0];
    const int* lengths = (const int*)d_in[1];
    float* out = (float*)d_out;
    float* groups = out;                               // B*G*GS*4 = 131072
    float* centers = out + (size_t)B_ * G_ * GS_ * 4;  // +3072
    float* mask = centers + (size_t)B_ * G_ * 3;       // +1024
    int* keep = (int*)d_ws;                            // B*G ints
    int* gl = keep + B_ * G_;                          // B ints

    hipLaunchKernelGGL(init_kernel, dim3(1), dim3(64), 0, stream, gl);
    hipLaunchKernelGGL(fps_cnms_kernel, dim3(B_), dim3(FPS_T), 0, stream,
                       pts, lengths, centers, keep);
    hipLaunchKernelGGL(group_kernel, dim3(B_ * G_), dim3(BQ_T), 0, stream,
                       pts, lengths, centers, keep, groups, gl);
    hipLaunchKernelGGL(mask_kernel, dim3(1), dim3(B_ * G_), 0, stream, gl, mask);
}

// Round 6
// 311.026 us; speedup vs baseline: 1.1163x; 1.0244x over previous
//
#include <hip/hip_runtime.h>
#include <math.h>

#define B_ 8
#define N_ 16384
#define G_ 128      // NUM_GROUPS
#define GS_ 32      // GROUP_SIZE
#define UK_ 128     // UPSCALE_K
#define FPS_T 512
#define FPS_W 8     // waves per FPS block
#define PPT 32      // points per thread (N_ / FPS_T)
#define BQ_T 512
#define BQ_W 8      // waves per group block

// No mul+add contraction anywhere in this TU: per-op IEEE rounding must match
// the numpy reference exactly (((dx*dx + dy*dy) + dz*dz), each op rounded).
#pragma clang fp contract(off)

typedef float v2f __attribute__((ext_vector_type(2)));

// 64-bit max-combine with a DPP-shifted copy of vv (old=0 == identity for max).
#define DPP64_MAXSTEP(vv, ctrl, rmask)                                          \
  {                                                                             \
    unsigned _lo = (unsigned)__builtin_amdgcn_update_dpp(                       \
        0, (int)(unsigned)((vv) & 0xffffffffull), (ctrl), (rmask), 0xf, false); \
    unsigned _hi = (unsigned)__builtin_amdgcn_update_dpp(                       \
        0, (int)(unsigned)((vv) >> 32), (ctrl), (rmask), 0xf, false);           \
    unsigned long long _tv = ((unsigned long long)_hi << 32) | _lo;             \
    if (_tv > (vv)) (vv) = _tv;                                                 \
  }

// Exact-rounding distance^2, matching numpy: ((dx*dx + dy*dy) + dz*dz), no FMA.
__device__ __forceinline__ float dist2(float x, float y, float z,
                                       float cx, float cy, float cz) {
    float dx = __fsub_rn(x, cx);
    float dy = __fsub_rn(y, cy);
    float dz = __fsub_rn(z, cz);
    return __fadd_rn(__fadd_rn(__fmul_rn(dx, dx), __fmul_rn(dy, dy)),
                     __fmul_rn(dz, dz));
}

// ---------------------------------------------------------------------------
// Kernel 0: zero gl (ws is poisoned 0xAA; must be zeroed before group_kernel).
// ---------------------------------------------------------------------------
__global__ void init_kernel(int* __restrict__ gl) {
    int t = threadIdx.x;
    if (t < B_) gl[t] = 0;
}

// ---------------------------------------------------------------------------
// Kernel 1: FPS, ONE block per batch + fused CNMS.
//
// r16 post-mortem of r15: active-CU VALUBusy ~78% => issue-bound, and the
// per-step OVERHEAD (~200 instr/thread: local argmax scan, DPP ladders,
// reduce, scaffolding) is paid by every wave: with 16 waves (4/SIMD) that's
// ~1600 cyc/step — as large as the distance work itself. Fix: 512 threads,
// PPT=32, 2 waves/SIMD — inner-loop issue invariant, overhead issue halves,
// barrier skew halves. Also: balanced fmax tree (fusable to v_max3_f32) and
// elementwise builtins so the backend picks pk ops freely.
// Structure: xy of all 16384 pts in 128KB LDS, z+mind in regs (64 payload
// VGPRs), one block per batch, u64 DPP argmax (bit-exact ties -> smallest n).
// ---------------------------------------------------------------------------
__global__ __launch_bounds__(FPS_T, 2) void fps_cnms_kernel(
    const float4* __restrict__ pts, const int* __restrict__ lengths,
    float* __restrict__ centers_out, int* __restrict__ keep_out) {
    const int b = blockIdx.x;
    const int t = threadIdx.x;
    const int lane = t & 63;
    const int wv = t >> 6;                               // 0..7
    const int len = lengths[b];
    const float4* p = pts + (size_t)b * N_;

    __shared__ float4 s_xy4[N_ / 2];                      // 128 KB: (xA,xB,yA,yB)
    __shared__ __align__(16) unsigned long long s_part[2][FPS_W];
    __shared__ float s_cen[G_][3];                        // centers for CNMS

    // Stage xy pairs -> LDS; z + running min-dist in registers. Pair j covers
    // slots 2j (A) and 2j+1 (B); slot s covers point n = s*512 + t.
    v2f zp[PPT / 2];
    v2f mp[PPT / 2];
#pragma unroll
    for (int j = 0; j < PPT / 2; j++) {
        int nA = (2 * j) * FPS_T + t;
        int nB = nA + FPS_T;
        float4 qA = p[nA];
        float4 qB = p[nB];
        s_xy4[j * FPS_T + t] = make_float4(qA.x, qB.x, qA.y, qB.y);
        v2f zz; zz.x = qA.z; zz.y = qB.z;
        zp[j] = zz;
        v2f mm;
        mm.x = (nA < len) ? INFINITY : -INFINITY;
        mm.y = (nB < len) ? INFINITY : -INFINITY;
        mp[j] = mm;
    }
    // Pin z so the RA has no incentive to re-derive it from global loads.
#pragma unroll
    for (int j = 0; j < PPT / 2; j++) asm volatile("" : "+v"(zp[j]));
    __syncthreads();

    int n = 0;   // winner index (uniform across the block)
    for (int k = 0; k < G_; k++) {
        float4 c = p[n];   // uniform broadcast load (L2-resident)
        if (t == 0) {
            centers_out[(b * G_ + k) * 3 + 0] = c.x;
            centers_out[(b * G_ + k) * 3 + 1] = c.y;
            centers_out[(b * G_ + k) * 3 + 2] = c.z;
            s_cen[k][0] = c.x; s_cen[k][1] = c.y; s_cen[k][2] = c.z;
        }
        if (k == G_ - 1) break;   // last argmax is discarded by the reference

        v2f cXX = {c.x, c.x};
        v2f cYY = {c.y, c.y};
        v2f cZZ = {c.z, c.z};

        // Min-only inner loop, native v2f ops: ~12 VALU per point-pair.
#pragma unroll
        for (int j = 0; j < PPT / 2; j++) {
            float4 xy = s_xy4[j * FPS_T + t];             // ds_read_b128, 2 pts
            v2f xv = {xy.x, xy.y};                        // (xA, xB)
            v2f yv = {xy.z, xy.w};                        // (yA, yB)
            v2f dx = xv - cXX;
            v2f dy = yv - cYY;
            v2f dz = zp[j] - cZZ;
            v2f dd = (dx * dx + dy * dy) + dz * dz;       // contract(off): exact
            mp[j] = __builtin_elementwise_min(mp[j], dd);
        }

        // Deferred thread-local value max: balanced tree (fusable to max3).
        v2f t8[8];
#pragma unroll
        for (int j = 0; j < 8; j++)
            t8[j] = __builtin_elementwise_max(mp[2 * j], mp[2 * j + 1]);
        v2f t4a = __builtin_elementwise_max(t8[0], t8[1]);
        v2f t4b = __builtin_elementwise_max(t8[2], t8[3]);
        v2f t4c = __builtin_elementwise_max(t8[4], t8[5]);
        v2f t4d = __builtin_elementwise_max(t8[6], t8[7]);
        v2f t2a = __builtin_elementwise_max(t4a, t4b);
        v2f t2b = __builtin_elementwise_max(t4c, t4d);
        v2f t1 = __builtin_elementwise_max(t2a, t2b);
        float bv = fmaxf(t1.x, t1.y);

        // Smallest slot holding bv (slot s covers n = s*512 + t).
        int bi = 0;
#pragma unroll
        for (int s = PPT - 1; s >= 0; s--) {
            float mv = (s & 1) ? mp[s >> 1].y : mp[s >> 1].x;
            if (mv == bv) bi = s;
        }

        // Monotone u32 key of bv (any non-NaN float, including +-inf).
        unsigned u = __float_as_uint(bv);
        u = (u & 0x80000000u) ? ~u : (u | 0x80000000u);
        int bn = (bi << 9) | t;           // global point index (bi*512 + t)
        unsigned long long v = ((unsigned long long)u << 32) | (unsigned)(~bn);

        // Wave argmax: u64 max == (max value, then min index among ties).
        DPP64_MAXSTEP(v, 0x111, 0xf);     // row_shl 1
        DPP64_MAXSTEP(v, 0x112, 0xf);     // row_shl 2
        DPP64_MAXSTEP(v, 0x114, 0xf);     // row_shl 4
        DPP64_MAXSTEP(v, 0x118, 0xf);     // row_shl 8
        DPP64_MAXSTEP(v, 0x142, 0xa);     // row_bcast15
        DPP64_MAXSTEP(v, 0x143, 0xc);     // row_bcast31 -> lane63 has wave max
        if (lane == 63) s_part[k & 1][wv] = v;
        __syncthreads();

        // Each 8-lane octet reads all 8 partials (same-address broadcast),
        // reduces in 3 DPP steps; lane7 of row 0 has the max; readlane(7).
        // Double-buffered s_part => one barrier per step is race-free.
        unsigned long long m = s_part[k & 1][lane & 7];
        DPP64_MAXSTEP(m, 0x111, 0xf);
        DPP64_MAXSTEP(m, 0x112, 0xf);
        DPP64_MAXSTEP(m, 0x114, 0xf);
        unsigned wlo = (unsigned)__builtin_amdgcn_readlane(
            (int)(unsigned)(m & 0xffffffffull), 7);
        n = (int)(~wlo);                  // decode index
    }

    __syncthreads();   // s_cen[127] written by t==0 after the break

    // ---- fused CNMS on wave 0 ----
    if (t < 64) {
        const float THR = (float)((2.0 * 0.1 * (1.0 - 0.7)) * (2.0 * 0.1 * (1.0 - 0.7)));
        float ax = s_cen[t][0],      ay = s_cen[t][1],      az = s_cen[t][2];
        float ex = s_cen[t + 64][0], ey = s_cen[t + 64][1], ez = s_cen[t + 64][2];
        bool k0 = false, k1 = false;
        for (int j = 0; j < G_; j++) {
            float jx = s_cen[j][0], jy = s_cen[j][1], jz = s_cen[j][2];
            bool c0 = k0 && (dist2(ax, ay, az, jx, jy, jz) < THR);
            bool c1 = k1 && (dist2(ex, ey, ez, jx, jy, jz) < THR);
            bool conflict = __any(c0 || c1);
            if (j == t)      k0 = !conflict;
            if (j == t + 64) k1 = !conflict;
        }
        keep_out[b * G_ + t]      = k0 ? 1 : 0;
        keep_out[b * G_ + t + 64] = k1 ? 1 : 0;
    }
}

// ---------------------------------------------------------------------------
// Kernel 2: per-(b,g) ball query (first 128 by index) + top-32 by energy +
// gather/normalize. One 512-thread block per group. (unchanged)
// ---------------------------------------------------------------------------
__global__ __launch_bounds__(BQ_T) void group_kernel(
    const float4* __restrict__ pts, const int* __restrict__ lengths,
    const float* __restrict__ centers, const int* __restrict__ keep,
    float* __restrict__ groups_out, int* __restrict__ gl) {
    const int bid = blockIdx.x;          // b*128 + g
    const int b = bid >> 7;
    const int t = threadIdx.x;
    const int lane = t & 63;
    const int wv = t >> 6;

    const float cx = centers[bid * 3 + 0];
    const float cy = centers[bid * 3 + 1];
    const float cz = centers[bid * 3 + 2];
    float4* out4 = (float4*)(groups_out + (size_t)bid * GS_ * 4);

    if (!keep[bid]) {
        if (t < GS_) {
            float4 o;
            o.x = __fdiv_rn(__fsub_rn(0.f, cx), 0.1f);
            o.y = __fdiv_rn(__fsub_rn(0.f, cy), 0.1f);
            o.z = __fdiv_rn(__fsub_rn(0.f, cz), 0.1f);
            o.w = 0.f;
            out4[t] = o;
        }
        return;
    }

    __shared__ int   s_widx[BQ_W][UK_];
    __shared__ float s_wen[BQ_W][UK_];
    __shared__ int   s_wcnt[BQ_W];
    __shared__ int   s_list[UK_];
    __shared__ float s_en[UK_];
    __shared__ int   s_ord[GS_];

    const int len = lengths[b];
    const float R2 = (float)(0.1 * 0.1);
    const float4* p = pts + (size_t)b * N_;

    // Per-wave ordered stream compaction over its contiguous eighth.
    {
        const int base0 = wv * (N_ / BQ_W);
        int cnt = 0;
        for (int it = 0; it < (N_ / BQ_W) / 64; it++) {
            int n = base0 + it * 64 + lane;
            float4 q = p[n];
            float d2 = dist2(q.x, q.y, q.z, cx, cy, cz);
            bool pred = (n < len) && (d2 <= R2);
            unsigned long long m = __ballot(pred);
            int prefix = __popcll(m & ((1ull << lane) - 1ull));
            int slot = cnt + prefix;
            if (pred && slot < UK_) { s_widx[wv][slot] = n; s_wen[wv][slot] = q.w; }
            cnt += __popcll(m);
        }
        if (lane == 0) s_wcnt[wv] = (cnt < UK_) ? cnt : UK_;
    }
    __syncthreads();

    int M = 0;
#pragma unroll
    for (int w = 0; w < BQ_W; w++) M += s_wcnt[w];
    if (M > UK_) M = UK_;

    // Ordered merge into unified first-M list.
    if (t < UK_ && t < M) {
        int j = t, w = 0;
        while (w < BQ_W - 1 && j >= s_wcnt[w]) { j -= s_wcnt[w]; w++; }
        s_list[t] = s_widx[w][j];
        s_en[t]   = s_wen[w][j];
    }
    __syncthreads();

    // top-32 by energy, tie -> smaller list position (matches lax.top_k)
    if (wv == 0) {
        float v0 = (lane < M) ? s_en[lane] : -INFINITY;
        float v1 = (lane + 64 < M) ? s_en[lane + 64] : -INFINITY;
        for (int k = 0; k < GS_; k++) {
            float bv; int bs;
            if (v0 >= v1) { bv = v0; bs = lane; }
            else          { bv = v1; bs = lane + 64; }
#pragma unroll
            for (int off = 32; off; off >>= 1) {
                float ov = __shfl_xor(bv, off);
                int   os = __shfl_xor(bs, off);
                bool tk = (ov > bv) || (ov == bv && os < bs);
                bv = tk ? ov : bv; bs = tk ? os : bs;
            }
            if (lane == 0) s_ord[k] = (bv == -INFINITY) ? -1 : bs;
            if (bs == lane)           v0 = -INFINITY;
            else if (bs == lane + 64) v1 = -INFINITY;
        }
    }
    __syncthreads();

    if (t < GS_) {
        int o0 = s_ord[0];
        int first = (o0 >= 0) ? s_list[o0] : -1;
        int ok = s_ord[t];
        int ti = (ok >= 0) ? s_list[ok] : -1;
        int f = (ti == -1) ? first : ti;
        float px = 0.f, py = 0.f, pz = 0.f, pw = 0.f;
        if (f >= 0) { float4 q = p[f]; px = q.x; py = q.y; pz = q.z; pw = q.w; }
        float4 o;
        o.x = __fdiv_rn(__fsub_rn(px, cx), 0.1f);
        o.y = __fdiv_rn(__fsub_rn(py, cy), 0.1f);
        o.z = __fdiv_rn(__fsub_rn(pz, cz), 0.1f);
        o.w = __fdiv_rn(pw, 0.1f);
        out4[t] = o;
    }
    if (t == 0 && M >= GS_) atomicAdd(&gl[b], 1);
}

// ---------------------------------------------------------------------------
// Kernel 3: embedding mask
// ---------------------------------------------------------------------------
__global__ void mask_kernel(const int* __restrict__ gl, float* __restrict__ mask_out) {
    int t = threadIdx.x;                 // 1024 threads
    int b = t >> 7, g = t & 127;
    mask_out[t] = (g < gl[b]) ? 1.0f : 0.0f;
}

extern "C" void kernel_launch(void* const* d_in, const int* in_sizes, int n_in,
                              void* d_out, int out_size, void* d_ws, size_t ws_size,
                              hipStream_t stream) {
    const float4* pts = (const float4*)d_in[0];
    const int* lengths = (const int*)d_in[1];
    float* out = (float*)d_out;
    float* groups = out;                               // B*G*GS*4 = 131072
    float* centers = out + (size_t)B_ * G_ * GS_ * 4;  // +3072
    float* mask = centers + (size_t)B_ * G_ * 3;       // +1024
    int* keep = (int*)d_ws;                            // B*G ints
    int* gl = keep + B_ * G_;                          // B ints

    hipLaunchKernelGGL(init_kernel, dim3(1), dim3(64), 0, stream, gl);
    hipLaunchKernelGGL(fps_cnms_kernel, dim3(B_), dim3(FPS_T), 0, stream,
                       pts, lengths, centers, keep);
    hipLaunchKernelGGL(group_kernel, dim3(B_ * G_), dim3(BQ_T), 0, stream,
                       pts, lengths, centers, keep, groups, gl);
    hipLaunchKernelGGL(mask_kernel, dim3(1), dim3(B_ * G_), 0, stream, gl, mask);
}